// Round 5
// baseline (111.239 us; speedup 1.0000x reference)
//
#include <hip/hip_runtime.h>
#include <hip/hip_cooperative_groups.h>

namespace cg = cooperative_groups;

#define EPS_F 1e-7f
#define NN 32        // N fixed at 32 by the problem setup
#define MARGIN 3     // conservative range margin (anchor units); fp slop ≤ 0.05
#define NSEG (NN * 6)
#define TPB 256      // 4 waves/block; 32 blocks -> 32 CUs busy
#define SLICES 8     // candidate-space slices per sample (coop path)
#define CAND_MAX 24576  // provable worst-case T ~19k + slack

// rl_coop v5: cooperative grid (SLICES, B) = 32 blocks. v4 (~14 µs) ran on
// only 4 CUs; its latency chains (LDS map walk + HBM-cold reg loads, all
// caches evicted by the 256 MiB poison fill) can't be hidden by one block
// per sample. v5 slices the flat candidate space across 8 blocks/sample:
//   - setup (sort/ranges/scan/cand map) replicated per block (~2 µs, runs
//     in parallel across blocks; it is NOT worth a cross-block handoff)
//   - each block: partial {loss,pos} over j = slice*TPB+t, stride 2048
//   - partials -> ws slots via device-scope atomicExch; grid.sync();
//     slice-0 blocks re-read coherently (atomicAdd(p,0)) and write out.
// gridDim.x==1 fallback (non-coop launch) skips sync and writes out
// directly, so a failed cooperative launch degrades, never breaks.
// Range derivation, exact fp32 predicate, overlap-mask first-match and
// rcp-GIoU are bit-identical to the verified kernel.
__global__ __launch_bounds__(TPB) void rl_coop(
    const float* __restrict__ reg,   // (B, A, 2)
    const float* __restrict__ ann,   // (B, N, 3)
    int c0, int A,
    float* __restrict__ ws,          // (B, gridDim.x, 2) partial slots
    float* __restrict__ out)         // (B,) final loss per sample
{
    const int s_blk = blockIdx.x;
    const int gridS = gridDim.x;
    const int b = blockIdx.y;
    const int t = threadIdx.x;
    const int wave = t >> 6;
    const int lane = t & 63;

    __shared__ float2 sh_se[NN];       // sorted (s,e), ascending length
    __shared__ int4   seg[NSEG];       // {l0, r0, lenL|(lenR<<16), start<<16|n<<8|lvl}
    __shared__ int    pfx[NSEG];       // counts, then inclusive prefix
    __shared__ unsigned segmask[NSEG]; // earlier-gt overlap mask per segment
    __shared__ unsigned cand32[CAND_MAX / 4];  // flat candidate -> segment id
    __shared__ float  sh_sz[8];
    __shared__ float  red_l[TPB / 64], red_p[TPB / 64];

    // SIZES as double-exprs cast to f32 — JAX weak-scalar promotion.
    if (t < 8) {
        const float szc[8] = {
            0.0f,
            (float)(2.23147392 * (22050.0 / 256.0)),
            (float)(2.62519274 * (22050.0 / 256.0)),
            (float)(3.74199546 * (22050.0 / 256.0)),
            (float)(5.78800454 * (22050.0 / 256.0)),
            (float)(8.02371882 * (22050.0 / 256.0)),
            __builtin_inff(), __builtin_inff()
        };
        sh_sz[t] = szc[t];
    }

    // Shfl-based stable rank sort by length (wave 0, lanes 0..31 only) —
    // identical to the verified kernel.
    if (t < NN) {
        const float* an = ann + (size_t)b * (size_t)NN * 3;
        const float s0 = an[t * 3 + 0];
        const float e0 = an[t * 3 + 1];
        const float len = e0 - s0;
        int rank = 0;
#pragma unroll
        for (int j = 0; j < NN; ++j) {
            const float lj = __shfl(len, j, 64);
            rank += (lj < len) || (lj == len && j < t);
        }
        sh_se[rank] = make_float2(s0, e0);
    }
    __syncthreads();

    // Per-(gt,lvl) conservative ranges — verified MARGIN superset logic —
    // plus the earlier-gt overlap mask.
    if (t < NSEG) {
        const int n   = t / 6;
        const int lvl = t - n * 6;
        const float2 se = sh_se[n];
        const float s = se.x, e = se.y;
        const float mid   = 0.5f * (s + e);
        const float halfL = 0.5f * (e - s);
        const float lo = sh_sz[lvl];
        const float hi = sh_sz[lvl + 1];
        const int   cnt = c0 >> lvl;
        const float inv   = __int_as_float((127 - lvl) << 23);  // 2^-lvl
        const float scale = __int_as_float((127 + lvl) << 23);  // 2^lvl

        // m(pt) = L/2 + |pt - mid|; band => |pt-mid| in [dlo, dhi).
        const float dlo = fmaxf(lo - halfL, 0.0f);
        const float dhi = hi - halfL;                // +inf at lvl 5 is fine
        const float prl = fmaxf(mid + dlo, s);       // right interval
        const float prh = fminf(mid + dhi, e);
        const float pll = fmaxf(mid - dhi, s);       // left interval
        const float plh = fminf(mid - dlo, e);

        int r0 = (int)floorf(prl * inv - 0.5f) - MARGIN;
        int r1 = (int)floorf(prh * inv - 0.5f) + MARGIN;
        int l0 = (int)floorf(pll * inv - 0.5f) - MARGIN;
        int l1 = (int)floorf(plh * inv - 0.5f) + MARGIN;
        r0 = max(r0, 0); r1 = min(r1, cnt - 1);
        l0 = max(l0, 0); l1 = min(l1, cnt - 1);
        if (r1 >= r0) l1 = min(l1, r0 - 1);          // disjoint union
        const int lenL = max(l1 - l0 + 1, 0);
        const int lenR = max(r1 - r0 + 1, 0);
        seg[t] = make_int4(l0, r0, lenL | (lenR << 16), (n << 8) | lvl);
        pfx[t] = lenL + lenR;

        // Anchor-pt span of this segment (same fp expr as the j-loop's pt,
        // so the span test is an exact superset of the in_gt condition).
        const int firstloc = lenL ? l0 : r0;
        const int lastloc  = lenR ? r1 : l1;
        const float ptmin = ((float)firstloc + 0.5f) * scale;
        const float ptmax = ((float)lastloc  + 0.5f) * scale;
        unsigned msk = 0u;
        for (int n2 = 0; n2 < n; ++n2) {
            const float2 o = sh_se[n2];
            if ((o.x <= ptmax) & (o.y >= ptmin)) msk |= (1u << n2);
        }
        segmask[t] = msk;
    }
    __syncthreads();

    // Wave-0 shfl inclusive scan over the 192 counts (3 chunks of 64).
    if (wave == 0) {
        int carry = 0;
#pragma unroll
        for (int k = 0; k < 3; ++k) {
            int v = pfx[k * 64 + lane];
#pragma unroll
            for (int o = 1; o < 64; o <<= 1) {
                const int u = __shfl_up(v, o, 64);
                v += (lane >= o) ? u : 0;
            }
            pfx[k * 64 + lane] = v + carry;
            carry += __shfl(v, 63, 64);   // chunk total, broadcast
        }
    }
    __syncthreads();
    const int T = min(pfx[NSEG - 1], CAND_MAX);   // clamp provably inactive

    // Fill the flat candidate->segment byte map (u32-packed); pack start
    // into seg.w high 16 bits (start < 24576 < 2^15).
    if (t < NSEG) {
        const int4 sg = seg[t];
        const int count = (sg.z & 0xffff) + (sg.z >> 16);
        const int start = pfx[t] - count;
        seg[t].w = sg.w | (start << 16);
        unsigned char* cbw = (unsigned char*)cand32;
        int i = start;
        const int end = min(start + count, CAND_MAX);
        const unsigned rep = 0x01010101u * (unsigned)t;
        while (i < end && (i & 3)) cbw[i++] = (unsigned char)t;
        for (; i + 4 <= end; i += 4) cand32[i >> 2] = rep;
        for (; i < end; ++i) cbw[i] = (unsigned char)t;
    }
    __syncthreads();

    const int twoc0 = 2 * c0;
    const unsigned char* cb = (const unsigned char*)cand32;
    float loss_sum = 0.0f, pos_sum = 0.0f;

    for (int j = s_blk * TPB + t; j < T; j += gridS * TPB) {
        const int sid = cb[j];                       // 1 LDS byte read
        const int4 sg = seg[sid];                    // 1 ds_read_b128
        unsigned msk = segmask[sid];                 // independent b32 read
        const int lenL  = sg.z & 0xffff;
        const int start = (int)(((unsigned)sg.w) >> 16);
        const int n     = (sg.w >> 8) & 0xff;
        const int lvl   = sg.w & 0xff;
        const int local = j - start;
        const int loc = (local < lenL) ? (sg.x + local) : (sg.y + (local - lenL));
        const float scale = __int_as_float((127 + lvl) << 23);  // 2^lvl
        const float inv   = __int_as_float((127 - lvl) << 23);  // 2^-lvl
        const int aoff = twoc0 - (twoc0 >> lvl);

        // Issue the global load EARLY — always in-bounds (loc in [0,cnt)),
        // overlaps with the predicate work below.
        const float2 g = ((const float2*)reg)[(size_t)b * A + (aoff + loc)];

        const float pt = ((float)loc + 0.5f) * scale;  // bit-exact anchor
        const float lo = sh_sz[lvl];
        const float hi = sh_sz[lvl + 1];
        const float2 se = sh_se[n];
        const float l = pt - se.x;
        const float r = se.y - pt;
        const float m = fmaxf(l, r);
        // EXACT reference predicate (fp32, same op order/compares).
        bool valid = (fminf(l, r) >= 0.0f) & (m >= lo) & (m < hi);

        // First-match via overlap mask: exact predicate only on the (rare)
        // earlier gts whose [s,e] intersects this segment's anchor span.
        while (valid && msk) {
            const int n2 = __builtin_ctz(msk);
            msk &= msk - 1u;
            const float2 o = sh_se[n2];
            const float l2 = pt - o.x;
            const float r2 = o.y - pt;
            const float m2 = fmaxf(l2, r2);
            if ((fminf(l2, r2) >= 0.0f) & (m2 >= lo) & (m2 < hi)) valid = false;
        }

        // GIoU epilogue (rcp; validated absmax 0 vs 3.9e-2 threshold).
        const float b0 = pt - l * inv;
        const float b1 = pt + r * inv;
        const float inter = fmaxf(fminf(b1, g.y) - fmaxf(b0, g.x), 0.0f);
        const float uni = (b1 - b0) + (g.y - g.x) - inter;
        const float iou = inter * __builtin_amdgcn_rcpf(uni + EPS_F);
        const float enc = fmaxf(b1, g.y) - fminf(b0, g.x);
        float giou = iou - (enc - uni) * __builtin_amdgcn_rcpf(enc + EPS_F);
        giou = fminf(fmaxf(giou, -1.0f), 1.0f);
        loss_sum += valid ? (1.0f - giou) : 0.0f;
        pos_sum  += valid ? 1.0f : 0.0f;
    }

    // In-block reduction: wave shfl + LDS cross-wave.
    for (int o = 32; o > 0; o >>= 1) {
        loss_sum += __shfl_down(loss_sum, o, 64);
        pos_sum  += __shfl_down(pos_sum,  o, 64);
    }
    if (lane == 0) { red_l[wave] = loss_sum; red_p[wave] = pos_sum; }
    __syncthreads();

    if (gridS == 1) {
        // Fallback (non-cooperative) path: single block per sample.
        if (t == 0) {
            float Ls = 0.0f, Ps = 0.0f;
#pragma unroll
            for (int w = 0; w < TPB / 64; ++w) { Ls += red_l[w]; Ps += red_p[w]; }
            out[b] = Ls / fmaxf(Ps, 1.0f);
        }
        return;
    }

    // Cooperative path: publish partial via device-scope atomics (coherent
    // across XCDs), grid-wide sync, slice-0 blocks reduce + divide.
    if (t == 0) {
        float Ls = 0.0f, Ps = 0.0f;
#pragma unroll
        for (int w = 0; w < TPB / 64; ++w) { Ls += red_l[w]; Ps += red_p[w]; }
        float* slot = ws + ((size_t)b * gridS + s_blk) * 2;
        atomicExch(&slot[0], Ls);
        atomicExch(&slot[1], Ps);
    }
    cg::this_grid().sync();

    if (s_blk == 0 && t == 0) {
        float Ls = 0.0f, Ps = 0.0f;
        for (int i = 0; i < gridS; ++i) {
            float* slot = ws + ((size_t)b * gridS + i) * 2;
            Ls += atomicAdd(&slot[0], 0.0f);   // coherent device-scope read
            Ps += atomicAdd(&slot[1], 0.0f);
        }
        out[b] = Ls / fmaxf(Ps, 1.0f);
    }
}

extern "C" void kernel_launch(void* const* d_in, const int* in_sizes, int n_in,
                              void* d_out, int out_size, void* d_ws, size_t ws_size,
                              hipStream_t stream) {
    const float* reg = (const float*)d_in[0];
    const float* ann = (const float*)d_in[1];
    // d_in[2] = class_id (unused); anchors d_in[3..8] are analytic, not read.
    const int c0 = in_sizes[3];
    const int A = in_sizes[3] + in_sizes[4] + in_sizes[5] +
                  in_sizes[6] + in_sizes[7] + in_sizes[8];
    const int B = out_size;                  // 4
    float* ws = (float*)d_ws;
    float* outp = (float*)d_out;

    void* args[] = { (void*)&reg, (void*)&ann, (void*)&c0, (void*)&A,
                     (void*)&ws, (void*)&outp };
    hipError_t err = hipLaunchCooperativeKernel(
        (const void*)rl_coop, dim3(SLICES, B), dim3(TPB), args, 0, stream);
    if (err != hipSuccess) {
        // Degrade gracefully: same kernel, one block per sample, no sync.
        rl_coop<<<dim3(1, B), TPB, 0, stream>>>(reg, ann, c0, A, ws, outp);
    }
}

// Round 6
// 74.009 us; speedup vs baseline: 1.5030x; 1.5030x over previous
//
#include <hip/hip_runtime.h>

#define EPS_F 1e-7f
#define NN 32        // N fixed at 32 by the problem setup
#define MARGIN 3     // conservative range margin (anchor units); fp slop ≤ 0.05
#define NSEG (NN * 6)
#define TPB 1024     // 16 waves: 4/SIMD for latency hiding
#define CHUNK 4      // software-pipeline factor for the candidate loop
#define CAND_MAX 24576  // provable worst-case T ~19k + slack

// rl_fused v6 = v4 (best, ~14 µs kernel) + manual software-pipelining.
// v4's residual cost was chained latency in dynamic-trip loops (hipcc
// emits load->waitcnt->use per iteration, nothing overlaps):
//   (a) candidate loop: cand[j]->seg[sid]->HBM reg load, ~1300 cy/cand
//   (b) setup segmask: up to 31 serialized LDS round-trips
// v6 fixes (a) with a CHUNK=4 static unroll (phase 1: issue 4 independent
// LDS+HBM chains; phase 2: compute from registers; inactive lanes clamp
// j->0 and fold 'act' into 'valid'), and (b) with a shfl-broadcast table
// (each lane caches sh_se[lane&31]; overlap test is unrolled VALU shfl,
// waves 0-2 fully active at t<192 so shfl is uniform).
// Range derivation, exact fp32 predicate, overlap-mask first-match and
// rcp-GIoU are bit-identical to v4; only scheduling changed.
// NO cooperative launch (v5: +35 µs under graph capture — never again).
__global__ __launch_bounds__(TPB) void rl_fused(
    const float* __restrict__ reg,   // (B, A, 2)
    const float* __restrict__ ann,   // (B, N, 3)
    int c0, int A,
    float* __restrict__ out)         // (B,) final loss per sample
{
    const int b = blockIdx.x;
    const int t = threadIdx.x;
    const int wave = t >> 6;
    const int lane = t & 63;

    __shared__ float2 sh_se[NN];       // sorted (s,e), ascending length
    __shared__ int4   seg[NSEG];       // {l0, r0, lenL|(lenR<<16), start<<16|n<<8|lvl}
    __shared__ int    pfx[NSEG];       // counts, then inclusive prefix
    __shared__ unsigned segmask[NSEG]; // earlier-gt overlap mask per segment
    __shared__ unsigned cand32[CAND_MAX / 4];  // flat candidate -> segment id
    __shared__ float  sh_sz[8];
    __shared__ float  red_l[TPB / 64], red_p[TPB / 64];

    // SIZES as double-exprs cast to f32 — JAX weak-scalar promotion.
    if (t < 8) {
        const float szc[8] = {
            0.0f,
            (float)(2.23147392 * (22050.0 / 256.0)),
            (float)(2.62519274 * (22050.0 / 256.0)),
            (float)(3.74199546 * (22050.0 / 256.0)),
            (float)(5.78800454 * (22050.0 / 256.0)),
            (float)(8.02371882 * (22050.0 / 256.0)),
            __builtin_inff(), __builtin_inff()
        };
        sh_sz[t] = szc[t];
    }

    // Shfl-based stable rank sort by length (wave 0, lanes 0..31 only) —
    // identical to the verified kernel.
    if (t < NN) {
        const float* an = ann + (size_t)b * (size_t)NN * 3;
        const float s0 = an[t * 3 + 0];
        const float e0 = an[t * 3 + 1];
        const float len = e0 - s0;
        int rank = 0;
#pragma unroll
        for (int j = 0; j < NN; ++j) {
            const float lj = __shfl(len, j, 64);
            rank += (lj < len) || (lj == len && j < t);
        }
        sh_se[rank] = make_float2(s0, e0);
    }
    __syncthreads();

    // Every lane caches sorted gt (s,e) for lane&31 -> 2 VGPR; the segmask
    // overlap test below reads it via __shfl (VALU, no LDS latency).
    float tsx, tsy;
    {
        const float2 tmp = sh_se[lane & 31];
        tsx = tmp.x; tsy = tmp.y;
    }

    // Per-(gt,lvl) conservative ranges — verified MARGIN superset logic —
    // plus the earlier-gt overlap mask. t<192 = waves 0..2 fully active.
    if (t < NSEG) {
        const int n   = t / 6;
        const int lvl = t - n * 6;
        const float2 se = sh_se[n];
        const float s = se.x, e = se.y;
        const float mid   = 0.5f * (s + e);
        const float halfL = 0.5f * (e - s);
        const float lo = sh_sz[lvl];
        const float hi = sh_sz[lvl + 1];
        const int   cnt = c0 >> lvl;
        const float inv   = __int_as_float((127 - lvl) << 23);  // 2^-lvl
        const float scale = __int_as_float((127 + lvl) << 23);  // 2^lvl

        // m(pt) = L/2 + |pt - mid|; band => |pt-mid| in [dlo, dhi).
        const float dlo = fmaxf(lo - halfL, 0.0f);
        const float dhi = hi - halfL;                // +inf at lvl 5 is fine
        const float prl = fmaxf(mid + dlo, s);       // right interval
        const float prh = fminf(mid + dhi, e);
        const float pll = fmaxf(mid - dhi, s);       // left interval
        const float plh = fminf(mid - dlo, e);

        int r0 = (int)floorf(prl * inv - 0.5f) - MARGIN;
        int r1 = (int)floorf(prh * inv - 0.5f) + MARGIN;
        int l0 = (int)floorf(pll * inv - 0.5f) - MARGIN;
        int l1 = (int)floorf(plh * inv - 0.5f) + MARGIN;
        r0 = max(r0, 0); r1 = min(r1, cnt - 1);
        l0 = max(l0, 0); l1 = min(l1, cnt - 1);
        if (r1 >= r0) l1 = min(l1, r0 - 1);          // disjoint union
        const int lenL = max(l1 - l0 + 1, 0);
        const int lenR = max(r1 - r0 + 1, 0);
        seg[t] = make_int4(l0, r0, lenL | (lenR << 16), (n << 8) | lvl);
        pfx[t] = lenL + lenR;

        // Anchor-pt span of this segment (same fp expr as the j-loop's pt,
        // so the span test is an exact superset of the in_gt condition).
        const int firstloc = lenL ? l0 : r0;
        const int lastloc  = lenR ? r1 : l1;
        const float ptmin = ((float)firstloc + 0.5f) * scale;
        const float ptmax = ((float)lastloc  + 0.5f) * scale;
        unsigned msk = 0u;
#pragma unroll
        for (int n2 = 0; n2 < NN - 1; ++n2) {
            const float ox = __shfl(tsx, n2, 64);    // uniform: waves 0-2 full
            const float oy = __shfl(tsy, n2, 64);
            msk |= ((n2 < n) & (ox <= ptmax) & (oy >= ptmin)) ? (1u << n2) : 0u;
        }
        segmask[t] = msk;
    }
    __syncthreads();

    // Wave-0 shfl inclusive scan over the 192 counts (3 chunks of 64).
    if (wave == 0) {
        int carry = 0;
#pragma unroll
        for (int k = 0; k < 3; ++k) {
            int v = pfx[k * 64 + lane];
#pragma unroll
            for (int o = 1; o < 64; o <<= 1) {
                const int u = __shfl_up(v, o, 64);
                v += (lane >= o) ? u : 0;
            }
            pfx[k * 64 + lane] = v + carry;
            carry += __shfl(v, 63, 64);   // chunk total, broadcast
        }
    }
    __syncthreads();
    const int T = min(pfx[NSEG - 1], CAND_MAX);   // clamp provably inactive

    // Fill the flat candidate->segment byte map (u32-packed); pack start
    // into seg.w high 16 bits (start < 24576 < 2^16).
    if (t < NSEG) {
        const int4 sg = seg[t];
        const int count = (sg.z & 0xffff) + (sg.z >> 16);
        const int start = pfx[t] - count;
        seg[t].w = sg.w | (start << 16);
        unsigned char* cbw = (unsigned char*)cand32;
        int i = start;
        const int end = min(start + count, CAND_MAX);
        const unsigned rep = 0x01010101u * (unsigned)t;
        while (i < end && (i & 3)) cbw[i++] = (unsigned char)t;
        for (; i + 4 <= end; i += 4) cand32[i >> 2] = rep;
        for (; i < end; ++i) cbw[i] = (unsigned char)t;
    }
    __syncthreads();

    const int twoc0 = 2 * c0;
    const unsigned char* cb = (const unsigned char*)cand32;
    const float2* reg2 = (const float2*)reg + (size_t)b * A;
    float loss_sum = 0.0f, pos_sum = 0.0f;

    for (int jb = t; jb < T; jb += TPB * CHUNK) {
        // ---- phase 1: decode + issue all CHUNK independent load chains ----
        float2 gk[CHUNK];
        float  ptk[CHUNK], lk[CHUNK], rk[CHUNK], lok[CHUNK], hik[CHUNK], invk[CHUNK];
        unsigned mskk[CHUNK];
        bool validk[CHUNK];
#pragma unroll
        for (int k = 0; k < CHUNK; ++k) {
            const int j = jb + k * TPB;
            const bool act = j < T;
            const int jj = act ? j : 0;              // clamp to a real candidate
            const int sid = cb[jj];                  // 1 LDS byte read
            const int4 sg = seg[sid];                // 1 ds_read_b128
            mskk[k] = segmask[sid];                  // independent b32 read
            const int lenL  = sg.z & 0xffff;
            const int start = (int)(((unsigned)sg.w) >> 16);
            const int n     = (sg.w >> 8) & 0xff;
            const int lvl   = sg.w & 0xff;
            const int local = jj - start;
            const int loc = (local < lenL) ? (sg.x + local) : (sg.y + (local - lenL));
            const float scale = __int_as_float((127 + lvl) << 23);  // 2^lvl
            invk[k] = __int_as_float((127 - lvl) << 23);            // 2^-lvl
            const int aoff = twoc0 - (twoc0 >> lvl);

            // Global load issued here — independent across k, all in flight.
            gk[k] = reg2[aoff + loc];

            const float pt = ((float)loc + 0.5f) * scale;  // bit-exact anchor
            ptk[k] = pt;
            lok[k] = sh_sz[lvl];
            hik[k] = sh_sz[lvl + 1];
            const float2 se = sh_se[n];
            const float l = pt - se.x;
            const float r = se.y - pt;
            lk[k] = l; rk[k] = r;
            const float m = fmaxf(l, r);
            // EXACT reference predicate (fp32, same op order/compares).
            validk[k] = act & (fminf(l, r) >= 0.0f) & (m >= lok[k]) & (m < hik[k]);
        }

        // ---- phase 2: first-match + GIoU from registers ----
#pragma unroll
        for (int k = 0; k < CHUNK; ++k) {
            bool valid = validk[k];
            unsigned msk = mskk[k];
            const float pt = ptk[k];
            const float lo = lok[k], hi = hik[k];
            // First-match via overlap mask: exact predicate only on the
            // (rare) earlier gts whose [s,e] intersects the anchor span.
            while (valid && msk) {
                const int n2 = __builtin_ctz(msk);
                msk &= msk - 1u;
                const float2 o = sh_se[n2];
                const float l2 = pt - o.x;
                const float r2 = o.y - pt;
                const float m2 = fmaxf(l2, r2);
                if ((fminf(l2, r2) >= 0.0f) & (m2 >= lo) & (m2 < hi)) valid = false;
            }

            // GIoU epilogue (rcp; validated absmax 0 vs 3.9e-2 threshold).
            const float inv = invk[k];
            const float2 g = gk[k];
            const float b0 = pt - lk[k] * inv;
            const float b1 = pt + rk[k] * inv;
            const float inter = fmaxf(fminf(b1, g.y) - fmaxf(b0, g.x), 0.0f);
            const float uni = (b1 - b0) + (g.y - g.x) - inter;
            const float iou = inter * __builtin_amdgcn_rcpf(uni + EPS_F);
            const float enc = fmaxf(b1, g.y) - fminf(b0, g.x);
            float giou = iou - (enc - uni) * __builtin_amdgcn_rcpf(enc + EPS_F);
            giou = fminf(fmaxf(giou, -1.0f), 1.0f);
            loss_sum += valid ? (1.0f - giou) : 0.0f;
            pos_sum  += valid ? 1.0f : 0.0f;
        }
    }

    // Wave reduce, cross-wave via LDS, final division in-block.
    for (int o = 32; o > 0; o >>= 1) {
        loss_sum += __shfl_down(loss_sum, o, 64);
        pos_sum  += __shfl_down(pos_sum,  o, 64);
    }
    if (lane == 0) { red_l[wave] = loss_sum; red_p[wave] = pos_sum; }
    __syncthreads();
    if (t < 16) {
        float Ls = red_l[t];
        float Ps = red_p[t];
#pragma unroll
        for (int o = 8; o > 0; o >>= 1) {
            Ls += __shfl_down(Ls, o, 16);
            Ps += __shfl_down(Ps, o, 16);
        }
        if (t == 0) out[b] = Ls / fmaxf(Ps, 1.0f);
    }
}

extern "C" void kernel_launch(void* const* d_in, const int* in_sizes, int n_in,
                              void* d_out, int out_size, void* d_ws, size_t ws_size,
                              hipStream_t stream) {
    const float* reg = (const float*)d_in[0];
    const float* ann = (const float*)d_in[1];
    // d_in[2] = class_id (unused); anchors d_in[3..8] are analytic, not read.
    const int c0 = in_sizes[3];
    const int A = in_sizes[3] + in_sizes[4] + in_sizes[5] +
                  in_sizes[6] + in_sizes[7] + in_sizes[8];
    const int B = out_size;                  // 4
    (void)d_ws; (void)ws_size;

    rl_fused<<<dim3(B), TPB, 0, stream>>>(reg, ann, c0, A, (float*)d_out);
}